// Round 7
// baseline (196.892 us; speedup 1.0000x reference)
//
#include <hip/hip_runtime.h>

typedef unsigned short ushort_t;
typedef unsigned int uint_t;
typedef __attribute__((ext_vector_type(8))) short short8v;
typedef __attribute__((ext_vector_type(4))) float f32x4;

__device__ __forceinline__ float bf2f(ushort_t u) {
    union { uint_t u; float f; } v; v.u = (uint_t)u << 16; return v.f;
}
__device__ __forceinline__ ushort_t f2bf(float f) {
    union { float f; uint_t u; } v; v.f = f;
    uint_t u = v.u;
    return (ushort_t)((u + 0x7fffu + ((u >> 16) & 1u)) >> 16);  // RNE
}

#define MFMA(A,B,C) __builtin_amdgcn_mfma_f32_16x16x32_bf16(A, B, C, 0, 0, 0)

// split 8 fp32 -> bf16 hi + bf16 lo fragments (in-register)
__device__ __forceinline__ void split8(float4 f0, float4 f1, short8v& h8, short8v& l8) {
    float v[8] = {f0.x, f0.y, f0.z, f0.w, f1.x, f1.y, f1.z, f1.w};
    union { short8v v; ushort_t s[8]; } H, L;
    #pragma unroll
    for (int e = 0; e < 8; ++e) {
        ushort_t h = f2bf(v[e]);
        H.s[e] = h;
        L.s[e] = f2bf(v[e] - bf2f(h));
    }
    h8 = H.v; l8 = L.v;
}

// ---------------- Kernel 1: pointwise conv + BN fold — MFMA (UNCHANGED from R6) ----
__global__ __launch_bounds__(256, 4) void k1_pwbn_mfma(
    const float* __restrict__ x, const float* __restrict__ w_in, const float* __restrict__ b_in,
    const float* __restrict__ gamma, const float* __restrict__ beta,
    const float* __restrict__ mean, const float* __restrict__ var,
    ushort_t* __restrict__ xbn)
{
    __shared__ short xsh[64][72];
    __shared__ short xsl[64][72];
    __shared__ short wfh[64][72];
    __shared__ short wfl[64][72];
    __shared__ float bef[64];

    int tid = threadIdx.x;
    int b   = blockIdx.x >> 10;
    int hw0 = (blockIdx.x & 1023) << 6;
    const float* xb = x + ((size_t)b << 22);

    #pragma unroll
    for (int u = 0; u < 2; ++u) {
        int idx = u * 256 + tid;
        int cp = idx >> 4, pq = idx & 15;
        int c0 = cp * 2, p0 = pq * 4;
        float4 fa = *(const float4*)(xb + (size_t)c0 * 65536 + hw0 + p0);
        float4 fb = *(const float4*)(xb + (size_t)(c0 + 1) * 65536 + hw0 + p0);
        float va[4] = {fa.x, fa.y, fa.z, fa.w};
        float vb[4] = {fb.x, fb.y, fb.z, fb.w};
        #pragma unroll
        for (int e = 0; e < 4; ++e) {
            ushort_t h0 = f2bf(va[e]), h1 = f2bf(vb[e]);
            ushort_t l0 = f2bf(va[e] - bf2f(h0)), l1 = f2bf(vb[e] - bf2f(h1));
            *(uint_t*)&xsh[p0 + e][c0] = (uint_t)h0 | ((uint_t)h1 << 16);
            *(uint_t*)&xsl[p0 + e][c0] = (uint_t)l0 | ((uint_t)l1 << 16);
        }
    }
    #pragma unroll
    for (int v = 0; v < 2; ++v) {
        int idx = v * 256 + tid;
        int o = idx >> 3, c0 = (idx & 7) * 8;
        float sc = gamma[o] * rsqrtf(var[o] + 1e-5f);
        float4 fa = *(const float4*)(w_in + o * 64 + c0);
        float4 fb = *(const float4*)(w_in + o * 64 + c0 + 4);
        float vv[8] = {fa.x, fa.y, fa.z, fa.w, fb.x, fb.y, fb.z, fb.w};
        union { int4 q; ushort_t s[8]; } ph, pl;
        #pragma unroll
        for (int e = 0; e < 8; ++e) {
            float wv = vv[e] * sc;
            ushort_t h = f2bf(wv);
            ph.s[e] = h;
            pl.s[e] = f2bf(wv - bf2f(h));
        }
        *(int4*)&wfh[o][c0] = ph.q;
        *(int4*)&wfl[o][c0] = pl.q;
    }
    if (tid < 64) {
        float inv = gamma[tid] * rsqrtf(var[tid] + 1e-5f);
        bef[tid] = (b_in[tid] - mean[tid]) * inv + beta[tid];
    }
    __syncthreads();

    int w = tid >> 6, l = tid & 63;
    int half = l >> 4, lr = l & 15;
    int k0 = half * 8;

    short8v bh[2], bl[2];
    #pragma unroll
    for (int kc = 0; kc < 2; ++kc) {
        bh[kc] = *(short8v*)&xsh[16 * w + lr][k0 + 32 * kc];
        bl[kc] = *(short8v*)&xsl[16 * w + lr][k0 + 32 * kc];
    }
    short8v ah[4][2], al[4][2];
    #pragma unroll
    for (int ot = 0; ot < 4; ++ot)
        #pragma unroll
        for (int kc = 0; kc < 2; ++kc) {
            ah[ot][kc] = *(short8v*)&wfh[16 * ot + lr][k0 + 32 * kc];
            al[ot][kc] = *(short8v*)&wfl[16 * ot + lr][k0 + 32 * kc];
        }

    ushort_t* xp = xbn + ((size_t)(b * 65536 + hw0 + 16 * w + lr) << 6);
    #pragma unroll
    for (int ot = 0; ot < 4; ++ot) {
        f32x4 acc = {0.f, 0.f, 0.f, 0.f};
        #pragma unroll
        for (int kc = 0; kc < 2; ++kc) {
            acc = MFMA(ah[ot][kc], bh[kc], acc);
            acc = MFMA(ah[ot][kc], bl[kc], acc);
            acc = MFMA(al[ot][kc], bh[kc], acc);
        }
        int o0 = 16 * ot + 4 * half;
        float4 bq = *(const float4*)&bef[o0];
        float bqs[4] = {bq.x, bq.y, bq.z, bq.w};
        ushort_t hs[4];
        #pragma unroll
        for (int rr = 0; rr < 4; ++rr) hs[rr] = f2bf(acc[rr] + bqs[rr]);
        *(uint2*)(xp + o0) = make_uint2((uint_t)hs[0] | ((uint_t)hs[1] << 16),
                                        (uint_t)hs[2] | ((uint_t)hs[3] << 16));
    }
}

// ---------------- Kernel 2 v3: MFMA attention, 3 blocks/CU, 5 barriers ----------------
// LDS (52.25 KB): A = g -> VWT ; B = V -> P~ ; C = qh ; D = ql ; E = S -> OutT (swizzled)
// Weights (wm, wo) read directly from global (L2-hot), split hi/lo in registers.
#define K2_A   0
#define K2_B   9216
#define K2_C   18432
#define K2_D   27648
#define K2_E   36864
#define K2_RS  53248
#define K2_TOT 53504

__global__ __launch_bounds__(256, 3) void k2_attn_v3(
    const ushort_t* __restrict__ xbn,
    const float* __restrict__ w_mask, const float* __restrict__ b_mask,
    const float* __restrict__ w_out,  const float* __restrict__ b_out,
    float* __restrict__ out)
{
    __shared__ char smem[K2_TOT];
    short* gb   = (short*)(smem + K2_A);
    short* vb   = (short*)(smem + K2_B);
    short* qhb  = (short*)(smem + K2_C);
    short* qlb  = (short*)(smem + K2_D);
    float* Sb   = (float*)(smem + K2_E);
    short* vwt  = (short*)(smem + K2_A);   // aliases g after G1
    short* pt   = (short*)(smem + K2_B);   // aliases V after G2
    float* outt = (float*)(smem + K2_E);   // aliases S after softmax
    float* rsv  = (float*)(smem + K2_RS);

    int tid = threadIdx.x;
    int wid = blockIdx.x;
    int b = wid >> 10, i = (wid >> 5) & 31, j = wid & 31;
    const ushort_t* xb = xbn + ((size_t)b << 22);

    // ---- stage g, V (raw bf16 row copies, pitch 72) ----
    {
        int t = tid >> 2, seg = tid & 3;
        int r = t & 7, s = t >> 3;
        int pr = i * 8 + 2 * r; if (pr >= 256) pr -= 8;
        int pc = j * 8 + 2 * s; if (pc >= 256) pc -= 8;
        const ushort_t* src = xb + (((size_t)((pr << 8) | pc)) << 6) + seg * 16;
        *(int4*)(gb + t * 72 + seg * 16)     = *(const int4*)src;
        *(int4*)(gb + t * 72 + seg * 16 + 8) = *(const int4*)(src + 8);
        int vr = i * 8 + (t >> 3), vc = j * 8 + (t & 7);
        const ushort_t* vsrc = xb + (((size_t)((vr << 8) | vc)) << 6) + seg * 16;
        *(int4*)(vb + t * 72 + seg * 16)     = *(const int4*)vsrc;
        *(int4*)(vb + t * 72 + seg * 16 + 8) = *(const int4*)(vsrc + 8);
    }
    __syncthreads();                                   // --- barrier 1

    int w = tid >> 6, l = tid & 63;
    int half = l >> 4, lr = l & 15;
    int mrow = (16 * w + lr) * 72;
    int kc0 = half * 8, kc1 = 32 + half * 8;
    int swz = lr & 7;                                  // S/OutT col4 XOR key (= row&7)

    // ---- G1: q = g @ wm^T + b_mask ; A = wm from GLOBAL (hi/lo in reg), B = g ----
    {
        const float* wmp = w_mask + (16 * w + lr) * 64;
        short8v amh0, aml0, amh1, aml1;
        split8(*(const float4*)(wmp + kc0), *(const float4*)(wmp + kc0 + 4), amh0, aml0);
        split8(*(const float4*)(wmp + kc1), *(const float4*)(wmp + kc1 + 4), amh1, aml1);
        float4 bm = *(const float4*)(b_mask + 16 * w + half * 4);
        float bmv[4] = {bm.x, bm.y, bm.z, bm.w};
        #pragma unroll
        for (int n = 0; n < 4; ++n) {
            int nrow = (16 * n + lr) * 72;
            short8v bg0 = *(short8v*)(gb + nrow + kc0);
            short8v bg1 = *(short8v*)(gb + nrow + kc1);
            f32x4 acc = {0.f, 0.f, 0.f, 0.f};
            acc = MFMA(amh0, bg0, acc);
            acc = MFMA(amh1, bg1, acc);
            acc = MFMA(aml0, bg0, acc);
            acc = MFMA(aml1, bg1, acc);
            ushort_t hs[4], ls[4];
            #pragma unroll
            for (int rr = 0; rr < 4; ++rr) {
                float qv = acc[rr] + bmv[rr];
                hs[rr] = f2bf(qv);
                ls[rr] = f2bf(qv - bf2f(hs[rr]));
            }
            int qoff = (16 * n + lr) * 72 + 16 * w + half * 4;
            *(uint2*)(qhb + qoff) = make_uint2((uint_t)hs[0] | ((uint_t)hs[1] << 16),
                                               (uint_t)hs[2] | ((uint_t)hs[3] << 16));
            *(uint2*)(qlb + qoff) = make_uint2((uint_t)ls[0] | ((uint_t)ls[1] << 16),
                                               (uint_t)ls[2] | ((uint_t)ls[3] << 16));
        }
    }
    __syncthreads();                                   // --- barrier 2

    // ---- G2: VWT = (V @ wo^T)^T -> into A (g dead) ; B = wo from GLOBAL ----
    {
        short8v av0 = *(short8v*)(vb + mrow + kc0);
        short8v av1 = *(short8v*)(vb + mrow + kc1);
        #pragma unroll
        for (int n = 0; n < 4; ++n) {
            const float* wop = w_out + (16 * n + lr) * 64;
            short8v bh0, bl0, bh1, bl1;
            split8(*(const float4*)(wop + kc0), *(const float4*)(wop + kc0 + 4), bh0, bl0);
            split8(*(const float4*)(wop + kc1), *(const float4*)(wop + kc1 + 4), bh1, bl1);
            f32x4 acc = {0.f, 0.f, 0.f, 0.f};
            acc = MFMA(av0, bh0, acc);
            acc = MFMA(av1, bh1, acc);
            acc = MFMA(av0, bl0, acc);
            acc = MFMA(av1, bl1, acc);
            ushort_t hs[4];
            #pragma unroll
            for (int rr = 0; rr < 4; ++rr) hs[rr] = f2bf(acc[rr]);
            int voff = (16 * n + lr) * 72 + 16 * w + half * 4;
            *(uint2*)(vwt + voff) = make_uint2((uint_t)hs[0] | ((uint_t)hs[1] << 16),
                                               (uint_t)hs[2] | ((uint_t)hs[3] << 16));
        }
    }
    // ---- G3: S = q @ q^T (3-term) -> E with XOR-swizzled col4 (same phase as G2) ----
    {
        short8v ah0 = *(short8v*)(qhb + mrow + kc0);
        short8v ah1 = *(short8v*)(qhb + mrow + kc1);
        short8v al0 = *(short8v*)(qlb + mrow + kc0);
        short8v al1 = *(short8v*)(qlb + mrow + kc1);
        #pragma unroll
        for (int n = 0; n < 4; ++n) {
            int nrow = (16 * n + lr) * 72;
            short8v bh0 = *(short8v*)(qhb + nrow + kc0);
            short8v bh1 = *(short8v*)(qhb + nrow + kc1);
            short8v bl0 = *(short8v*)(qlb + nrow + kc0);
            short8v bl1 = *(short8v*)(qlb + nrow + kc1);
            f32x4 acc = {0.f, 0.f, 0.f, 0.f};
            acc = MFMA(ah0, bh0, acc);
            acc = MFMA(ah1, bh1, acc);
            acc = MFMA(ah0, bl0, acc);
            acc = MFMA(ah1, bl1, acc);
            acc = MFMA(al0, bh0, acc);
            acc = MFMA(al1, bh1, acc);
            int srow = 16 * n + lr;
            int c4s = (4 * w + half) ^ swz;
            *(f32x4*)(Sb + srow * 64 + c4s * 4) = acc;
        }
    }
    __syncthreads();                                   // --- barrier 3

    // ---- softmax: wave-local (quad shfl) ; P~ -> B (V dead) ----
    {
        int row = tid >> 2, p = tid & 3;
        int rsw = row & 7;
        const float* srow = Sb + row * 64;
        f32x4 s4[4];
        #pragma unroll
        for (int qq = 0; qq < 4; ++qq)
            s4[qq] = *(const f32x4*)(srow + (p * 4 + qq) * 4);   // physical order
        float m = -1e30f;
        #pragma unroll
        for (int qq = 0; qq < 4; ++qq)
            m = fmaxf(m, fmaxf(fmaxf(s4[qq][0], s4[qq][1]), fmaxf(s4[qq][2], s4[qq][3])));
        m = fmaxf(m, __shfl_xor(m, 1));
        m = fmaxf(m, __shfl_xor(m, 2));
        float ssum = 0.f;
        #pragma unroll
        for (int qq = 0; qq < 4; ++qq) {
            int ucol4 = (p * 4 + qq) ^ rsw;                      // logical u-base/4
            ushort_t hs[4];
            #pragma unroll
            for (int e = 0; e < 4; ++e) {
                ushort_t h = f2bf(__expf(s4[qq][e] - m));
                ssum += bf2f(h);
                hs[e] = h;
            }
            *(uint2*)(pt + row * 72 + ucol4 * 4) =
                make_uint2((uint_t)hs[0] | ((uint_t)hs[1] << 16),
                           (uint_t)hs[2] | ((uint_t)hs[3] << 16));
        }
        ssum += __shfl_xor(ssum, 1);
        ssum += __shfl_xor(ssum, 2);
        if (p == 0) rsv[row] = 1.0f / ssum;
    }
    __syncthreads();                                   // --- barrier 4

    // ---- G4: out = P~ @ VWT^T ; epilogue /rs + b_out -> OutT into E (S dead) ----
    {
        short8v ap0 = *(short8v*)(pt + mrow + kc0);
        short8v ap1 = *(short8v*)(pt + mrow + kc1);
        float4 rv = *(const float4*)(rsv + 16 * w + half * 4);
        float rvv[4] = {rv.x, rv.y, rv.z, rv.w};
        #pragma unroll
        for (int n = 0; n < 4; ++n) {
            int nrow = (16 * n + lr) * 72;
            short8v bv0 = *(short8v*)(vwt + nrow + kc0);
            short8v bv1 = *(short8v*)(vwt + nrow + kc1);
            f32x4 acc = {0.f, 0.f, 0.f, 0.f};
            acc = MFMA(ap0, bv0, acc);
            acc = MFMA(ap1, bv1, acc);
            int orow = 16 * n + lr;
            float bo = b_out[orow];
            int c4s = (4 * w + half) ^ swz;
            f32x4 wv = {acc[0] * rvv[0] + bo, acc[1] * rvv[1] + bo,
                        acc[2] * rvv[2] + bo, acc[3] * rvv[3] + bo};
            *(f32x4*)(outt + orow * 64 + c4s * 4) = wv;
        }
    }
    __syncthreads();                                   // --- barrier 5

    // ---- coalesced global store (swizzled LDS read) ----
    {
        float* ob = out + ((size_t)b << 22);
        int base = (i * 8) * 256 + j * 8;
        for (int pp = 0; pp < 16; ++pp) {
            int e = pp * 256 + tid;
            int o = e >> 6, t = e & 63;
            float val = outt[o * 64 + (((t >> 2) ^ (o & 7)) << 2) + (t & 3)];
            ob[((size_t)o << 16) + base + ((t >> 3) << 8) + (t & 7)] = val;
        }
    }
}

extern "C" void kernel_launch(void* const* d_in, const int* in_sizes, int n_in,
                              void* d_out, int out_size, void* d_ws, size_t ws_size,
                              hipStream_t stream) {
    const float* x      = (const float*)d_in[0];
    const float* w_in   = (const float*)d_in[1];
    const float* b_in   = (const float*)d_in[2];
    const float* gamma  = (const float*)d_in[3];
    const float* beta   = (const float*)d_in[4];
    const float* mean   = (const float*)d_in[5];
    const float* var    = (const float*)d_in[6];
    const float* w_mask = (const float*)d_in[7];
    const float* b_mask = (const float*)d_in[8];
    const float* w_out  = (const float*)d_in[9];
    const float* b_out  = (const float*)d_in[10];
    float* out = (float*)d_out;
    ushort_t* xbn = (ushort_t*)d_ws;   // 4*65536*64 bf16 = 33.5 MB

    hipLaunchKernelGGL(k1_pwbn_mfma, dim3(4096), dim3(256), 0, stream,
                       x, w_in, b_in, gamma, beta, mean, var, xbn);
    hipLaunchKernelGGL(k2_attn_v3, dim3(4096), dim3(256), 0, stream,
                       xbn, w_mask, b_mask, w_out, b_out, out);
}

// Round 8
// 186.947 us; speedup vs baseline: 1.0532x; 1.0532x over previous
//
#include <hip/hip_runtime.h>

typedef unsigned short ushort_t;
typedef unsigned int uint_t;
typedef __attribute__((ext_vector_type(8))) short short8v;
typedef __attribute__((ext_vector_type(4))) float f32x4;

__device__ __forceinline__ float bf2f(ushort_t u) {
    union { uint_t u; float f; } v; v.u = (uint_t)u << 16; return v.f;
}
__device__ __forceinline__ ushort_t f2bf(float f) {
    union { float f; uint_t u; } v; v.f = f;
    uint_t u = v.u;
    return (ushort_t)((u + 0x7fffu + ((u >> 16) & 1u)) >> 16);  // RNE
}

#define MFMA(A,B,C) __builtin_amdgcn_mfma_f32_16x16x32_bf16(A, B, C, 0, 0, 0)

// split 8 fp32 -> bf16 hi + bf16 lo fragments (in-register)
__device__ __forceinline__ void split8(float4 f0, float4 f1, short8v& h8, short8v& l8) {
    float v[8] = {f0.x, f0.y, f0.z, f0.w, f1.x, f1.y, f1.z, f1.w};
    union { short8v v; ushort_t s[8]; } H, L;
    #pragma unroll
    for (int e = 0; e < 8; ++e) {
        ushort_t h = f2bf(v[e]);
        H.s[e] = h;
        L.s[e] = f2bf(v[e] - bf2f(h));
    }
    h8 = H.v; l8 = L.v;
}

// ---------------- Kernel 1: pointwise conv + BN fold — MFMA (UNCHANGED, proven) ----
__global__ __launch_bounds__(256, 4) void k1_pwbn_mfma(
    const float* __restrict__ x, const float* __restrict__ w_in, const float* __restrict__ b_in,
    const float* __restrict__ gamma, const float* __restrict__ beta,
    const float* __restrict__ mean, const float* __restrict__ var,
    ushort_t* __restrict__ xbn)
{
    __shared__ short xsh[64][72];
    __shared__ short xsl[64][72];
    __shared__ short wfh[64][72];
    __shared__ short wfl[64][72];
    __shared__ float bef[64];

    int tid = threadIdx.x;
    int b   = blockIdx.x >> 10;
    int hw0 = (blockIdx.x & 1023) << 6;
    const float* xb = x + ((size_t)b << 22);

    #pragma unroll
    for (int u = 0; u < 2; ++u) {
        int idx = u * 256 + tid;
        int cp = idx >> 4, pq = idx & 15;
        int c0 = cp * 2, p0 = pq * 4;
        float4 fa = *(const float4*)(xb + (size_t)c0 * 65536 + hw0 + p0);
        float4 fb = *(const float4*)(xb + (size_t)(c0 + 1) * 65536 + hw0 + p0);
        float va[4] = {fa.x, fa.y, fa.z, fa.w};
        float vb[4] = {fb.x, fb.y, fb.z, fb.w};
        #pragma unroll
        for (int e = 0; e < 4; ++e) {
            ushort_t h0 = f2bf(va[e]), h1 = f2bf(vb[e]);
            ushort_t l0 = f2bf(va[e] - bf2f(h0)), l1 = f2bf(vb[e] - bf2f(h1));
            *(uint_t*)&xsh[p0 + e][c0] = (uint_t)h0 | ((uint_t)h1 << 16);
            *(uint_t*)&xsl[p0 + e][c0] = (uint_t)l0 | ((uint_t)l1 << 16);
        }
    }
    #pragma unroll
    for (int v = 0; v < 2; ++v) {
        int idx = v * 256 + tid;
        int o = idx >> 3, c0 = (idx & 7) * 8;
        float sc = gamma[o] * rsqrtf(var[o] + 1e-5f);
        float4 fa = *(const float4*)(w_in + o * 64 + c0);
        float4 fb = *(const float4*)(w_in + o * 64 + c0 + 4);
        float vv[8] = {fa.x, fa.y, fa.z, fa.w, fb.x, fb.y, fb.z, fb.w};
        union { int4 q; ushort_t s[8]; } ph, pl;
        #pragma unroll
        for (int e = 0; e < 8; ++e) {
            float wv = vv[e] * sc;
            ushort_t h = f2bf(wv);
            ph.s[e] = h;
            pl.s[e] = f2bf(wv - bf2f(h));
        }
        *(int4*)&wfh[o][c0] = ph.q;
        *(int4*)&wfl[o][c0] = pl.q;
    }
    if (tid < 64) {
        float inv = gamma[tid] * rsqrtf(var[tid] + 1e-5f);
        bef[tid] = (b_in[tid] - mean[tid]) * inv + beta[tid];
    }
    __syncthreads();

    int w = tid >> 6, l = tid & 63;
    int half = l >> 4, lr = l & 15;
    int k0 = half * 8;

    short8v bh[2], bl[2];
    #pragma unroll
    for (int kc = 0; kc < 2; ++kc) {
        bh[kc] = *(short8v*)&xsh[16 * w + lr][k0 + 32 * kc];
        bl[kc] = *(short8v*)&xsl[16 * w + lr][k0 + 32 * kc];
    }
    short8v ah[4][2], al[4][2];
    #pragma unroll
    for (int ot = 0; ot < 4; ++ot)
        #pragma unroll
        for (int kc = 0; kc < 2; ++kc) {
            ah[ot][kc] = *(short8v*)&wfh[16 * ot + lr][k0 + 32 * kc];
            al[ot][kc] = *(short8v*)&wfl[16 * ot + lr][k0 + 32 * kc];
        }

    ushort_t* xp = xbn + ((size_t)(b * 65536 + hw0 + 16 * w + lr) << 6);
    #pragma unroll
    for (int ot = 0; ot < 4; ++ot) {
        f32x4 acc = {0.f, 0.f, 0.f, 0.f};
        #pragma unroll
        for (int kc = 0; kc < 2; ++kc) {
            acc = MFMA(ah[ot][kc], bh[kc], acc);
            acc = MFMA(ah[ot][kc], bl[kc], acc);
            acc = MFMA(al[ot][kc], bh[kc], acc);
        }
        int o0 = 16 * ot + 4 * half;
        float4 bq = *(const float4*)&bef[o0];
        float bqs[4] = {bq.x, bq.y, bq.z, bq.w};
        ushort_t hs[4];
        #pragma unroll
        for (int rr = 0; rr < 4; ++rr) hs[rr] = f2bf(acc[rr] + bqs[rr]);
        *(uint2*)(xp + o0) = make_uint2((uint_t)hs[0] | ((uint_t)hs[1] << 16),
                                        (uint_t)hs[2] | ((uint_t)hs[3] << 16));
    }
}

// ---------------- Kernel 2 v4: register-softmax MFMA attention, 38 KB LDS ----------
// Weights prefetched per-lane into REGISTERS during staging (one row each: m/n-split).
// S never touches LDS. 5 barriers. Buffers: g->VWT, V->P~, qh, ql (->OutT), red, red2.
#define K4_G    0
#define K4_V    9216
#define K4_QH   18432
#define K4_QL   27648
#define K4_RED  36864
#define K4_RED2 37888
#define K4_TOT  38912

__global__ __launch_bounds__(256, 4) void k2_attn_v4(
    const ushort_t* __restrict__ xbn,
    const float* __restrict__ w_mask, const float* __restrict__ b_mask,
    const float* __restrict__ w_out,  const float* __restrict__ b_out,
    float* __restrict__ out)
{
    __shared__ char smem[K4_TOT];
    short* gb   = (short*)(smem + K4_G);
    short* vb   = (short*)(smem + K4_V);
    short* qhb  = (short*)(smem + K4_QH);
    short* qlb  = (short*)(smem + K4_QL);
    short* vwt  = (short*)(smem + K4_G);    // aliases g after G1
    short* pt   = (short*)(smem + K4_V);    // aliases V after G2
    float* outt = (float*)(smem + K4_QH);   // aliases qh/ql after G3 (16 KB)
    float* red  = (float*)(smem + K4_RED);  // [t][w] max partials
    float* red2 = (float*)(smem + K4_RED2); // [t][w] sum partials

    int tid = threadIdx.x;
    int wid = blockIdx.x;
    int b = wid >> 10, i = (wid >> 5) & 31, j = wid & 31;
    const ushort_t* xb = xbn + ((size_t)b << 22);

    int w = tid >> 6, l = tid & 63;
    int half = l >> 4, lr = l & 15;
    int mrow = (16 * w + lr) * 72;
    int kc0 = half * 8, kc1 = 32 + half * 8;

    // ---- weight prefetch (per-lane own row; latency hidden behind staging + G1) ----
    const float* wmp = w_mask + (16 * w + lr) * 64;
    const float* wop = w_out  + (16 * w + lr) * 64;
    float4 wmA = *(const float4*)(wmp + kc0), wmB = *(const float4*)(wmp + kc0 + 4);
    float4 wmC = *(const float4*)(wmp + kc1), wmD = *(const float4*)(wmp + kc1 + 4);
    float4 woA = *(const float4*)(wop + kc0), woB = *(const float4*)(wop + kc0 + 4);
    float4 woC = *(const float4*)(wop + kc1), woD = *(const float4*)(wop + kc1 + 4);

    // ---- stage g, V (raw bf16 row copies, pitch 72) ----
    {
        int t = tid >> 2, seg = tid & 3;
        int r = t & 7, s = t >> 3;
        int pr = i * 8 + 2 * r; if (pr >= 256) pr -= 8;
        int pc = j * 8 + 2 * s; if (pc >= 256) pc -= 8;
        const ushort_t* src = xb + (((size_t)((pr << 8) | pc)) << 6) + seg * 16;
        *(int4*)(gb + t * 72 + seg * 16)     = *(const int4*)src;
        *(int4*)(gb + t * 72 + seg * 16 + 8) = *(const int4*)(src + 8);
        int vr = i * 8 + (t >> 3), vc = j * 8 + (t & 7);
        const ushort_t* vsrc = xb + (((size_t)((vr << 8) | vc)) << 6) + seg * 16;
        *(int4*)(vb + t * 72 + seg * 16)     = *(const int4*)vsrc;
        *(int4*)(vb + t * 72 + seg * 16 + 8) = *(const int4*)(vsrc + 8);
    }
    __syncthreads();                                   // --- barrier 1

    // ---- G1 (m-split): q = g @ wm^T + b_mask ; A = wm row from regs, B = g ----
    {
        short8v amh0, aml0, amh1, aml1;
        split8(wmA, wmB, amh0, aml0);
        split8(wmC, wmD, amh1, aml1);
        float4 bm = *(const float4*)(b_mask + 16 * w + half * 4);
        float bmv[4] = {bm.x, bm.y, bm.z, bm.w};
        #pragma unroll
        for (int n = 0; n < 4; ++n) {
            int nrow = (16 * n + lr) * 72;
            short8v bg0 = *(short8v*)(gb + nrow + kc0);
            short8v bg1 = *(short8v*)(gb + nrow + kc1);
            f32x4 acc = {0.f, 0.f, 0.f, 0.f};
            acc = MFMA(amh0, bg0, acc);
            acc = MFMA(amh1, bg1, acc);
            acc = MFMA(aml0, bg0, acc);
            acc = MFMA(aml1, bg1, acc);
            ushort_t hs[4], ls[4];
            #pragma unroll
            for (int rr = 0; rr < 4; ++rr) {
                float qv = acc[rr] + bmv[rr];
                hs[rr] = f2bf(qv);
                ls[rr] = f2bf(qv - bf2f(hs[rr]));
            }
            int qoff = (16 * n + lr) * 72 + 16 * w + half * 4;   // qT[t][o]
            *(uint2*)(qhb + qoff) = make_uint2((uint_t)hs[0] | ((uint_t)hs[1] << 16),
                                               (uint_t)hs[2] | ((uint_t)hs[3] << 16));
            *(uint2*)(qlb + qoff) = make_uint2((uint_t)ls[0] | ((uint_t)ls[1] << 16),
                                               (uint_t)ls[2] | ((uint_t)ls[3] << 16));
        }
    }
    __syncthreads();                                   // --- barrier 2

    // ---- G2 (n-split): VWT[o][u] = (V @ wo^T)^T ; B = wo row from regs ----
    {
        short8v bh0, bl0, bh1, bl1;
        split8(woA, woB, bh0, bl0);
        split8(woC, woD, bh1, bl1);
        #pragma unroll
        for (int mm = 0; mm < 4; ++mm) {
            int arow = (16 * mm + lr) * 72;
            short8v av0 = *(short8v*)(vb + arow + kc0);
            short8v av1 = *(short8v*)(vb + arow + kc1);
            f32x4 acc = {0.f, 0.f, 0.f, 0.f};
            acc = MFMA(av0, bh0, acc);
            acc = MFMA(av1, bh1, acc);
            acc = MFMA(av0, bl0, acc);
            acc = MFMA(av1, bl1, acc);
            ushort_t hs[4];
            #pragma unroll
            for (int rr = 0; rr < 4; ++rr) hs[rr] = f2bf(acc[rr]);
            int voff = (16 * w + lr) * 72 + 16 * mm + 4 * half;  // VWT[o][u]
            *(uint2*)(vwt + voff) = make_uint2((uint_t)hs[0] | ((uint_t)hs[1] << 16),
                                               (uint_t)hs[2] | ((uint_t)hs[3] << 16));
        }
    }
    // ---- G3 (m-split, same phase): S tiles stay in REGISTERS ----
    f32x4 sreg[4];
    {
        short8v ah0 = *(short8v*)(qhb + mrow + kc0);
        short8v ah1 = *(short8v*)(qhb + mrow + kc1);
        short8v al0 = *(short8v*)(qlb + mrow + kc0);
        short8v al1 = *(short8v*)(qlb + mrow + kc1);
        #pragma unroll
        for (int n = 0; n < 4; ++n) {
            int nrow = (16 * n + lr) * 72;
            short8v bh0 = *(short8v*)(qhb + nrow + kc0);
            short8v bh1 = *(short8v*)(qhb + nrow + kc1);
            short8v bl0 = *(short8v*)(qlb + nrow + kc0);
            short8v bl1 = *(short8v*)(qlb + nrow + kc1);
            f32x4 acc = {0.f, 0.f, 0.f, 0.f};
            acc = MFMA(ah0, bh0, acc);
            acc = MFMA(ah1, bh1, acc);
            acc = MFMA(ah0, bl0, acc);
            acc = MFMA(ah1, bl1, acc);
            acc = MFMA(al0, bh0, acc);
            acc = MFMA(al1, bh1, acc);
            sreg[n] = acc;          // S[u = 16w+4h+rr][t = 16n+lr]
        }
        // wave-partial column max over u in [16w, 16w+16)
        #pragma unroll
        for (int n = 0; n < 4; ++n) {
            float pm = fmaxf(fmaxf(sreg[n][0], sreg[n][1]), fmaxf(sreg[n][2], sreg[n][3]));
            pm = fmaxf(pm, __shfl_xor(pm, 16));
            pm = fmaxf(pm, __shfl_xor(pm, 32));
            if (half == 0) red[(16 * n + lr) * 4 + w] = pm;
        }
    }
    __syncthreads();                                   // --- barrier 3

    // ---- softmax finish in registers: exp, write P~[t][u] bf16, partial sums ----
    {
        #pragma unroll
        for (int n = 0; n < 4; ++n) {
            int t = 16 * n + lr;
            float4 r4 = *(const float4*)&red[t * 4];
            float m = fmaxf(fmaxf(r4.x, r4.y), fmaxf(r4.z, r4.w));
            ushort_t hs[4];
            float ps = 0.f;
            #pragma unroll
            for (int rr = 0; rr < 4; ++rr) {
                ushort_t h = f2bf(__expf(sreg[n][rr] - m));
                ps += bf2f(h);
                hs[rr] = h;
            }
            *(uint2*)(pt + t * 72 + 16 * w + 4 * half) =
                make_uint2((uint_t)hs[0] | ((uint_t)hs[1] << 16),
                           (uint_t)hs[2] | ((uint_t)hs[3] << 16));
            ps += __shfl_xor(ps, 16);
            ps += __shfl_xor(ps, 32);
            if (half == 0) red2[t * 4 + w] = ps;
        }
    }
    __syncthreads();                                   // --- barrier 4

    // ---- G4 (n-split): out = P~ @ VWT^T ; /rowsum + b_out -> OutT[o][t] swizzled ----
    {
        short8v bv0 = *(short8v*)(vwt + mrow + kc0);   // VWT row o = 16w+lr
        short8v bv1 = *(short8v*)(vwt + mrow + kc1);
        float bo = b_out[16 * w + lr];
        int swz = lr & 7;
        #pragma unroll
        for (int mm = 0; mm < 4; ++mm) {
            int arow = (16 * mm + lr) * 72;
            short8v ap0 = *(short8v*)(pt + arow + kc0);
            short8v ap1 = *(short8v*)(pt + arow + kc1);
            f32x4 acc = {0.f, 0.f, 0.f, 0.f};
            acc = MFMA(ap0, bv0, acc);
            acc = MFMA(ap1, bv1, acc);
            f32x4 wv;
            #pragma unroll
            for (int rr = 0; rr < 4; ++rr) {
                int t = 16 * mm + 4 * half + rr;
                float4 s4 = *(const float4*)&red2[t * 4];
                float inv = 1.0f / (s4.x + s4.y + s4.z + s4.w);
                wv[rr] = acc[rr] * inv + bo;
            }
            int c4s = (4 * mm + half) ^ swz;
            *(f32x4*)(outt + (16 * w + lr) * 64 + c4s * 4) = wv;
        }
    }
    __syncthreads();                                   // --- barrier 5

    // ---- coalesced global store (swizzled LDS read) ----
    {
        float* ob = out + ((size_t)b << 22);
        int base = (i * 8) * 256 + j * 8;
        for (int pp = 0; pp < 16; ++pp) {
            int e = pp * 256 + tid;
            int o = e >> 6, t = e & 63;
            float val = outt[o * 64 + (((t >> 2) ^ (o & 7)) << 2) + (t & 3)];
            ob[((size_t)o << 16) + base + ((t >> 3) << 8) + (t & 7)] = val;
        }
    }
}

extern "C" void kernel_launch(void* const* d_in, const int* in_sizes, int n_in,
                              void* d_out, int out_size, void* d_ws, size_t ws_size,
                              hipStream_t stream) {
    const float* x      = (const float*)d_in[0];
    const float* w_in   = (const float*)d_in[1];
    const float* b_in   = (const float*)d_in[2];
    const float* gamma  = (const float*)d_in[3];
    const float* beta   = (const float*)d_in[4];
    const float* mean   = (const float*)d_in[5];
    const float* var    = (const float*)d_in[6];
    const float* w_mask = (const float*)d_in[7];
    const float* b_mask = (const float*)d_in[8];
    const float* w_out  = (const float*)d_in[9];
    const float* b_out  = (const float*)d_in[10];
    float* out = (float*)d_out;
    ushort_t* xbn = (ushort_t*)d_ws;   // 4*65536*64 bf16 = 33.5 MB

    hipLaunchKernelGGL(k1_pwbn_mfma, dim3(4096), dim3(256), 0, stream,
                       x, w_in, b_in, gamma, beta, mean, var, xbn);
    hipLaunchKernelGGL(k2_attn_v4, dim3(4096), dim3(256), 0, stream,
                       xbn, w_mask, b_mask, w_out, b_out, out);
}